// Round 7
// baseline (992.794 us; speedup 1.0000x reference)
//
#include <hip/hip_runtime.h>
#include <hip/hip_bf16.h>

// GAT 3-layer (PPI-style) on MI355X. ALL float tensors are fp32 (per the
// reference dtypes — the collapse signature of R2-R6 proved the bf16-input
// assumption wrong). edge_index is (2,E) planar, int32 or int64 (device
// flag). Output fp32.
// Pipeline: device-built dst-CSR; one wave per dst node (segment max ->
// denom -> message accumulation, shuffle reductions, no hot-path atomics);
// layer 3 aggregates in 64-dim h-space and applies W3 afterwards
// (linearity), with attention logits from w_as = W3@a3s / w_ad = W3@a3d
// fused into layer 2's epilogue.

__device__ __forceinline__ float lrelu(float s) { return (s >= 0.f) ? s : 0.2f * s; }

// ---------------- edge dtype detection: (2,E) planar ----------------
// int64 values < 2^31: odd int32 words all zero. int32 node IDs: ~never.

__global__ void detect_kernel(const int* __restrict__ ei, int* __restrict__ flag) {
    int t = threadIdx.x;  // 64 lanes
    int v = ei[2 * t + 1];
    unsigned long long b = __ballot(v == 0);
    if (t == 0) *flag = (b == ~0ULL) ? 1 : 0;
}

__device__ __forceinline__ int edge_at(const void* ei, int is64, long long idx) {
    return is64 ? (int)((const long long*)ei)[idx] : ((const int*)ei)[idx];
}

// ---------------- CSR build ----------------

__global__ void deg_init_kernel(int* __restrict__ deg, int N) {
    int t = blockIdx.x * blockDim.x + threadIdx.x;
    if (t < N) deg[t] = 1;  // self-loop
}

__global__ void deg_count_kernel(const void* __restrict__ ei, const int* __restrict__ flag,
                                 int* __restrict__ deg, int E) {
    int t = blockIdx.x * blockDim.x + threadIdx.x;
    if (t < E) {
        int dst = edge_at(ei, *flag, (long long)E + t);  // row 1 = dst
        atomicAdd(&deg[dst], 1);
    }
}

__global__ __launch_bounds__(1024)
void scan_kernel(const int* __restrict__ deg, int* __restrict__ row_ptr,
                 int* __restrict__ cursor, int N) {
    __shared__ int sums[1024];
    int t = threadIdx.x;
    int chunk = (N + 1023) >> 10;
    int lo = t * chunk;
    int hi = lo + chunk; if (hi > N) hi = N;
    if (lo > N) lo = N;
    int s = 0;
    for (int i = lo; i < hi; ++i) s += deg[i];
    sums[t] = s;
    __syncthreads();
    for (int off = 1; off < 1024; off <<= 1) {
        int v = (t >= off) ? sums[t - off] : 0;
        __syncthreads();
        sums[t] += v;
        __syncthreads();
    }
    int run = (t == 0) ? 0 : sums[t - 1];
    for (int i = lo; i < hi; ++i) {
        row_ptr[i] = run;
        cursor[i] = run;
        run += deg[i];
    }
    if (t == 0) row_ptr[N] = sums[1023];
}

__global__ void scatter_kernel(const void* __restrict__ ei, const int* __restrict__ flag,
                               int* __restrict__ cursor, int* __restrict__ adj, int E, int N) {
    int t = blockIdx.x * blockDim.x + threadIdx.x;
    if (t < E) {
        int is64 = *flag;
        int src = edge_at(ei, is64, t);
        int dst = edge_at(ei, is64, (long long)E + t);
        int pos = atomicAdd(&cursor[dst], 1);
        adj[pos] = src;
    } else if (t < E + N) {
        int n2 = t - E;
        int pos = atomicAdd(&cursor[n2], 1);
        adj[pos] = n2;  // self-loop
    }
}

// ---------------- w_as = W3 @ a3_src, w_ad = W3 @ a3_dst (64 each) --------

__global__ void w3a_kernel(const float* __restrict__ W3,
                           const float* __restrict__ a3s,
                           const float* __restrict__ a3d,
                           float* __restrict__ w_as, float* __restrict__ w_ad) {
    int t = threadIdx.x;  // 128 threads
    if (t >= 128) return;
    int k = t & 63;
    const float* a = (t < 64) ? a3s : a3d;
    float s = 0.f;
    for (int c = 0; c < 242; ++c) s = fmaf(W3[k * 242 + c], a[c], s);
    if (t < 64) w_as[k] = s; else w_ad[k] = s;
}

// ---------------- GEMM + alpha (layers 1 & 2: 64 output cols, H=8, C=8) ----
// Safe for in-place X==XW: each block only reads its own 4 rows (via LDS).

template <int K>
__global__ __launch_bounds__(256)
void gemm_alpha8(const float* __restrict__ X, const float* __restrict__ W,
                 const float* __restrict__ a_src, const float* __restrict__ a_dst,
                 float* __restrict__ XW, float* __restrict__ As, float* __restrict__ Ad,
                 int N) {
    __shared__ float wsh[K * 64];
    __shared__ float xsh[4][K];
    for (int i = threadIdx.x; i < K * 64; i += 256) wsh[i] = W[i];
    int wave = threadIdx.x >> 6, lane = threadIdx.x & 63;
    int node = blockIdx.x * 4 + wave;
    bool valid = node < N;
    const float* xr = X + (size_t)(valid ? node : 0) * K;
    for (int i = lane; i < K; i += 64) xsh[wave][i] = xr[i];
    __syncthreads();
    if (!valid) return;
    float acc = 0.f;
#pragma unroll 8
    for (int k = 0; k < K; ++k) acc = fmaf(xsh[wave][k], wsh[k * 64 + lane], acc);
    XW[(size_t)node * 64 + lane] = acc;
    int h = lane >> 3, c = lane & 7;
    float s = acc * a_src[h * 8 + c];
    float d = acc * a_dst[h * 8 + c];
    s += __shfl_xor(s, 1); s += __shfl_xor(s, 2); s += __shfl_xor(s, 4);
    d += __shfl_xor(d, 1); d += __shfl_xor(d, 2); d += __shfl_xor(d, 4);
    if (c == 0) {
        As[node * 8 + h] = s;
        Ad[node * 8 + h] = d;
    }
}

// ---------------- Aggregation (layers 1 & 2): one wave per dst node --------
// Lane layout: head h = lane>>3 (matches output column lane = h*8 + c),
// slot = lane&7. Phases 1/2 lane-parallel (reduce over slot bits 1,2,4);
// phase 3 per-edge serial with per-lane weight recompute.
// WITH_A3: also emit layer-3 logits As3/Ad3 from the relu'd output.

template <bool WITH_A3>
__global__ __launch_bounds__(256)
void agg_h8c8(const float* __restrict__ XW, const float* __restrict__ As,
              const float* __restrict__ Ad, const int* __restrict__ row_ptr,
              const int* __restrict__ adj, const float* __restrict__ bias,
              float* __restrict__ OUT,
              const float* __restrict__ w_as, const float* __restrict__ w_ad,
              float* __restrict__ As3, float* __restrict__ Ad3, int N) {
    int wave = threadIdx.x >> 6, lane = threadIdx.x & 63;
    int node = blockIdx.x * 4 + wave;
    if (node >= N) return;
    int beg = row_ptr[node], end = row_ptr[node + 1];
    int h = lane >> 3;
    int slot = lane & 7;
    float ad = Ad[node * 8 + h];

    // phase 1: segment max for head h
    float emax = -1e30f;
    for (int p = beg; p < end; p += 8) {
        int idx = p + slot;
        float e = -1e30f;
        if (idx < end) e = lrelu(As[(size_t)adj[idx] * 8 + h] + ad);
        emax = fmaxf(emax, e);
    }
    emax = fmaxf(emax, __shfl_xor(emax, 1));
    emax = fmaxf(emax, __shfl_xor(emax, 2));
    emax = fmaxf(emax, __shfl_xor(emax, 4));

    // phase 2: softmax denominator for head h
    float denom = 0.f;
    for (int p = beg; p < end; p += 8) {
        int idx = p + slot;
        if (idx < end) {
            float e = lrelu(As[(size_t)adj[idx] * 8 + h] + ad);
            denom += expf(e - emax);
        }
    }
    denom += __shfl_xor(denom, 1);
    denom += __shfl_xor(denom, 2);
    denom += __shfl_xor(denom, 4);

    // phase 3: message accumulation, one edge at a time
    float acc = 0.f;
    for (int idx = beg; idx < end; ++idx) {
        int src = adj[idx];  // wave-uniform
        float e = lrelu(As[(size_t)src * 8 + h] + ad);
        float pv = expf(e - emax);
        acc = fmaf(pv, XW[(size_t)src * 64 + lane], acc);
    }

    float v = fmaxf(acc / (denom + 1e-16f) + bias[lane], 0.f);
    OUT[(size_t)node * 64 + lane] = v;

    if (WITH_A3) {
        float s3 = v * w_as[lane];
        float d3 = v * w_ad[lane];
#pragma unroll
        for (int m = 1; m <= 32; m <<= 1) {
            s3 += __shfl_xor(s3, m);
            d3 += __shfl_xor(d3, m);
        }
        if (lane == 0) {
            As3[node] = s3;
            Ad3[node] = d3;
        }
    }
}

// ---------------- Layer 3: aggregate h2 (64-dim), then @W3 + bias/relu/
// pairwise-softmax, all fused. One wave per dst node; W3 staged in LDS. -----

__global__ __launch_bounds__(256)
void agg3_kernel(const float* __restrict__ H2, const float* __restrict__ As3,
                 const float* __restrict__ Ad3, const int* __restrict__ row_ptr,
                 const int* __restrict__ adj, const float* __restrict__ W3,
                 const float* __restrict__ bias,
                 float* __restrict__ OUT, int N) {
    __shared__ float w3sh[64 * 244];  // stride 244 for float4 + pad
    __shared__ float msh[4][64];
    for (int i = threadIdx.x; i < 64 * 242; i += 256) {
        int k = i / 242, c = i - k * 242;
        w3sh[k * 244 + c] = W3[i];
    }
    if (threadIdx.x < 64) {
        w3sh[threadIdx.x * 244 + 242] = 0.f;
        w3sh[threadIdx.x * 244 + 243] = 0.f;
    }
    __syncthreads();

    int wave = threadIdx.x >> 6, lane = threadIdx.x & 63;
    int node = blockIdx.x * 4 + wave;
    if (node >= N) return;
    int beg = row_ptr[node], end = row_ptr[node + 1];
    float ad = Ad3[node];

    // phase 1: segment max
    float emax = -1e30f;
    for (int p = beg; p < end; p += 64) {
        int idx = p + lane;
        float e = -1e30f;
        if (idx < end) e = lrelu(As3[adj[idx]] + ad);
        emax = fmaxf(emax, e);
    }
#pragma unroll
    for (int m = 32; m >= 1; m >>= 1) emax = fmaxf(emax, __shfl_xor(emax, m));

    // phase 2: denominator
    float denom = 0.f;
    for (int p = beg; p < end; p += 64) {
        int idx = p + lane;
        if (idx < end) denom += expf(lrelu(As3[adj[idx]] + ad) - emax);
    }
#pragma unroll
    for (int m = 32; m >= 1; m >>= 1) denom += __shfl_xor(denom, m);
    float inv = 1.f / (denom + 1e-16f);

    // phase 3: h-space message accumulation
    float acc = 0.f;
    for (int idx = beg; idx < end; ++idx) {
        int src = adj[idx];
        float pv = expf(lrelu(As3[src] + ad) - emax);
        acc = fmaf(pv, H2[(size_t)src * 64 + lane], acc);
    }

    msh[wave][lane] = acc * inv;  // same-wave LDS round-trip

    int c0 = lane * 4;  // lanes 0..60 carry channels
    if (c0 < 242) {
        float o0 = 0.f, o1 = 0.f, o2 = 0.f, o3 = 0.f;
#pragma unroll 8
        for (int k = 0; k < 64; ++k) {
            float m = msh[wave][k];
            const float4 w = *(const float4*)(w3sh + k * 244 + c0);
            o0 = fmaf(m, w.x, o0);
            o1 = fmaf(m, w.y, o1);
            o2 = fmaf(m, w.z, o2);
            o3 = fmaf(m, w.w, o3);
        }
        size_t base = (size_t)node * 242 + c0;
        float v0 = fmaxf(o0 + bias[c0], 0.f);
        float v1 = fmaxf(o1 + bias[c0 + 1], 0.f);
        float m01 = fmaxf(v0, v1);
        float e0 = expf(v0 - m01), e1 = expf(v1 - m01);
        float r01 = 1.f / (e0 + e1);
        OUT[base]     = e0 * r01;
        OUT[base + 1] = e1 * r01;
        if (c0 + 2 < 242) {
            float v2 = fmaxf(o2 + bias[c0 + 2], 0.f);
            float v3 = fmaxf(o3 + bias[c0 + 3], 0.f);
            float m23 = fmaxf(v2, v3);
            float e2 = expf(v2 - m23), e3 = expf(v3 - m23);
            float r23 = 1.f / (e2 + e3);
            OUT[base + 2] = e2 * r23;
            OUT[base + 3] = e3 * r23;
        }
    }
}

// ---------------- launch ----------------

extern "C" void kernel_launch(void* const* d_in, const int* in_sizes, int n_in,
                              void* d_out, int out_size, void* d_ws, size_t ws_size,
                              hipStream_t stream) {
    const float* x   = (const float*)d_in[0];
    const void*  ei  = d_in[1];  // (2,E) planar; int32 or int64 via device flag
    const float* W1  = (const float*)d_in[2];
    const float* a1s = (const float*)d_in[3];
    const float* a1d = (const float*)d_in[4];
    const float* b1  = (const float*)d_in[5];
    const float* W2  = (const float*)d_in[6];
    const float* a2s = (const float*)d_in[7];
    const float* a2d = (const float*)d_in[8];
    const float* b2  = (const float*)d_in[9];
    const float* W3  = (const float*)d_in[10];
    const float* a3s = (const float*)d_in[11];
    const float* a3d = (const float*)d_in[12];
    const float* b3  = (const float*)d_in[13];
    float* out = (float*)d_out;

    const int N = in_sizes[0] / 128;  // 50000
    const int E = in_sizes[1] / 2;    // 800000

    char* w = (char*)d_ws;
    auto alloc = [&](size_t bytes) {
        char* p = w;
        w += (bytes + 255) & ~(size_t)255;
        return p;
    };
    int*   flag    = (int*)alloc(4);
    int*   deg     = (int*)alloc((size_t)N * 4);
    int*   row_ptr = (int*)alloc(((size_t)N + 1) * 4);
    int*   cursor  = (int*)alloc((size_t)N * 4);
    int*   adj     = (int*)alloc((size_t)(E + N) * 4);
    float* As      = (float*)alloc((size_t)N * 8 * 4);
    float* Ad      = (float*)alloc((size_t)N * 8 * 4);
    float* As3     = (float*)alloc((size_t)N * 4);
    float* Ad3     = (float*)alloc((size_t)N * 4);
    float* w_as    = (float*)alloc(64 * 4);
    float* w_ad    = (float*)alloc(64 * 4);
    float* bufA    = (float*)alloc((size_t)N * 64 * 4);
    float* bufB    = (float*)alloc((size_t)N * 64 * 4);
    // total ~33.3 MB

    // CSR over dst (includes self-loops)
    detect_kernel<<<1, 64, 0, stream>>>((const int*)ei, flag);
    deg_init_kernel<<<(N + 255) / 256, 256, 0, stream>>>(deg, N);
    deg_count_kernel<<<(E + 255) / 256, 256, 0, stream>>>(ei, flag, deg, E);
    scan_kernel<<<1, 1024, 0, stream>>>(deg, row_ptr, cursor, N);
    scatter_kernel<<<(E + N + 255) / 256, 256, 0, stream>>>(ei, flag, cursor, adj, E, N);
    w3a_kernel<<<1, 128, 0, stream>>>(W3, a3s, a3d, w_as, w_ad);

    int nb4 = (N + 3) / 4;

    // Layer 1: x -> bufA (xw1), agg -> bufB (h1)
    gemm_alpha8<128><<<nb4, 256, 0, stream>>>(x, W1, a1s, a1d, bufA, As, Ad, N);
    agg_h8c8<false><<<nb4, 256, 0, stream>>>(bufA, As, Ad, row_ptr, adj, b1, bufB,
                                             nullptr, nullptr, nullptr, nullptr, N);
    // Layer 2: bufB -> bufB in-place (xw2), agg -> bufA (h2) + As3/Ad3 epilogue
    gemm_alpha8<64><<<nb4, 256, 0, stream>>>(bufB, W2, a2s, a2d, bufB, As, Ad, N);
    agg_h8c8<true><<<nb4, 256, 0, stream>>>(bufB, As, Ad, row_ptr, adj, b2, bufA,
                                            w_as, w_ad, As3, Ad3, N);
    // Layer 3: aggregate h2, then @W3 + bias + relu + pairwise softmax -> out
    agg3_kernel<<<nb4, 256, 0, stream>>>(bufA, As3, Ad3, row_ptr, adj, W3, b3, out, N);
}

// Round 8
// 600.639 us; speedup vs baseline: 1.6529x; 1.6529x over previous
//
#include <hip/hip_runtime.h>
#include <hip/hip_bf16.h>

// GAT 3-layer (PPI-style) on MI355X. fp32 inputs/outputs; edge_index (2,E)
// planar, int32/int64 via device flag.
// R7 -> R8: (1) agg3 split into no-LDS aggregation + LDS-W3 gemm3 epilogue
// (agg3's 62KB LDS capped occupancy at 20% -> latency-bound at 385us);
// (2) single-pass aggregation: no max-subtraction (logits O(1), exp safe in
// fp32; p/sum(p) identical), denominator accumulated per-lane in the same
// loop as the message (every lane sees every edge -> no shuffles);
// (3) manual 4x edge unroll for memory-level parallelism.

__device__ __forceinline__ float lrelu(float s) { return (s >= 0.f) ? s : 0.2f * s; }

// ---------------- edge dtype detection: (2,E) planar ----------------

__global__ void detect_kernel(const int* __restrict__ ei, int* __restrict__ flag) {
    int t = threadIdx.x;  // 64 lanes
    int v = ei[2 * t + 1];
    unsigned long long b = __ballot(v == 0);
    if (t == 0) *flag = (b == ~0ULL) ? 1 : 0;
}

__device__ __forceinline__ int edge_at(const void* ei, int is64, long long idx) {
    return is64 ? (int)((const long long*)ei)[idx] : ((const int*)ei)[idx];
}

// ---------------- CSR build ----------------

__global__ void deg_init_kernel(int* __restrict__ deg, int N) {
    int t = blockIdx.x * blockDim.x + threadIdx.x;
    if (t < N) deg[t] = 1;  // self-loop
}

__global__ void deg_count_kernel(const void* __restrict__ ei, const int* __restrict__ flag,
                                 int* __restrict__ deg, int E) {
    int t = blockIdx.x * blockDim.x + threadIdx.x;
    if (t < E) {
        int dst = edge_at(ei, *flag, (long long)E + t);  // row 1 = dst
        atomicAdd(&deg[dst], 1);
    }
}

__global__ __launch_bounds__(1024)
void scan_kernel(const int* __restrict__ deg, int* __restrict__ row_ptr,
                 int* __restrict__ cursor, int N) {
    __shared__ int sums[1024];
    int t = threadIdx.x;
    int chunk = (N + 1023) >> 10;
    int lo = t * chunk;
    int hi = lo + chunk; if (hi > N) hi = N;
    if (lo > N) lo = N;
    int s = 0;
    for (int i = lo; i < hi; ++i) s += deg[i];
    sums[t] = s;
    __syncthreads();
    for (int off = 1; off < 1024; off <<= 1) {
        int v = (t >= off) ? sums[t - off] : 0;
        __syncthreads();
        sums[t] += v;
        __syncthreads();
    }
    int run = (t == 0) ? 0 : sums[t - 1];
    for (int i = lo; i < hi; ++i) {
        row_ptr[i] = run;
        cursor[i] = run;
        run += deg[i];
    }
    if (t == 0) row_ptr[N] = sums[1023];
}

__global__ void scatter_kernel(const void* __restrict__ ei, const int* __restrict__ flag,
                               int* __restrict__ cursor, int* __restrict__ adj, int E, int N) {
    int t = blockIdx.x * blockDim.x + threadIdx.x;
    if (t < E) {
        int is64 = *flag;
        int src = edge_at(ei, is64, t);
        int dst = edge_at(ei, is64, (long long)E + t);
        int pos = atomicAdd(&cursor[dst], 1);
        adj[pos] = src;
    } else if (t < E + N) {
        int n2 = t - E;
        int pos = atomicAdd(&cursor[n2], 1);
        adj[pos] = n2;  // self-loop
    }
}

// ---------------- w_as = W3 @ a3_src, w_ad = W3 @ a3_dst (64 each) --------

__global__ void w3a_kernel(const float* __restrict__ W3,
                           const float* __restrict__ a3s,
                           const float* __restrict__ a3d,
                           float* __restrict__ w_as, float* __restrict__ w_ad) {
    int t = threadIdx.x;  // 128 threads
    if (t >= 128) return;
    int k = t & 63;
    const float* a = (t < 64) ? a3s : a3d;
    float s = 0.f;
    for (int c = 0; c < 242; ++c) s = fmaf(W3[k * 242 + c], a[c], s);
    if (t < 64) w_as[k] = s; else w_ad[k] = s;
}

// ---------------- GEMM + alpha (layers 1 & 2: 64 output cols, H=8, C=8) ----
// Safe for in-place X==XW: each block only reads its own 4 rows (via LDS).

template <int K>
__global__ __launch_bounds__(256)
void gemm_alpha8(const float* __restrict__ X, const float* __restrict__ W,
                 const float* __restrict__ a_src, const float* __restrict__ a_dst,
                 float* __restrict__ XW, float* __restrict__ As, float* __restrict__ Ad,
                 int N) {
    __shared__ float wsh[K * 64];
    __shared__ float xsh[4][K];
    for (int i = threadIdx.x; i < K * 64; i += 256) wsh[i] = W[i];
    int wave = threadIdx.x >> 6, lane = threadIdx.x & 63;
    int node = blockIdx.x * 4 + wave;
    bool valid = node < N;
    const float* xr = X + (size_t)(valid ? node : 0) * K;
    for (int i = lane; i < K; i += 64) xsh[wave][i] = xr[i];
    __syncthreads();
    if (!valid) return;
    float acc = 0.f;
#pragma unroll 8
    for (int k = 0; k < K; ++k) acc = fmaf(xsh[wave][k], wsh[k * 64 + lane], acc);
    XW[(size_t)node * 64 + lane] = acc;
    int h = lane >> 3, c = lane & 7;
    float s = acc * a_src[h * 8 + c];
    float d = acc * a_dst[h * 8 + c];
    s += __shfl_xor(s, 1); s += __shfl_xor(s, 2); s += __shfl_xor(s, 4);
    d += __shfl_xor(d, 1); d += __shfl_xor(d, 2); d += __shfl_xor(d, 4);
    if (c == 0) {
        As[node * 8 + h] = s;
        Ad[node * 8 + h] = d;
    }
}

// ---------------- Aggregation (layers 1 & 2): one wave per dst node --------
// SINGLE PASS: every lane iterates every edge; p = exp(leaky(As[src,h]+ad))
// is identical across the 8 lanes of head h; den accumulates per-lane (no
// reduction needed). 4x unrolled for memory-level parallelism.
// WITH_A3: also emit layer-3 logits As3/Ad3 from the relu'd output.

template <bool WITH_A3>
__global__ __launch_bounds__(256)
void agg_h8c8(const float* __restrict__ XW, const float* __restrict__ As,
              const float* __restrict__ Ad, const int* __restrict__ row_ptr,
              const int* __restrict__ adj, const float* __restrict__ bias,
              float* __restrict__ OUT,
              const float* __restrict__ w_as, const float* __restrict__ w_ad,
              float* __restrict__ As3, float* __restrict__ Ad3, int N) {
    int wave = threadIdx.x >> 6, lane = threadIdx.x & 63;
    int node = blockIdx.x * 4 + wave;
    if (node >= N) return;
    int beg = row_ptr[node], end = row_ptr[node + 1];
    int h = lane >> 3;
    float ad = Ad[node * 8 + h];

    float acc = 0.f, den = 0.f;
    int idx = beg;
    for (; idx + 4 <= end; idx += 4) {
        int s0 = adj[idx], s1 = adj[idx + 1], s2 = adj[idx + 2], s3 = adj[idx + 3];
        float e0 = As[(size_t)s0 * 8 + h];
        float e1 = As[(size_t)s1 * 8 + h];
        float e2 = As[(size_t)s2 * 8 + h];
        float e3 = As[(size_t)s3 * 8 + h];
        float x0 = XW[(size_t)s0 * 64 + lane];
        float x1 = XW[(size_t)s1 * 64 + lane];
        float x2 = XW[(size_t)s2 * 64 + lane];
        float x3 = XW[(size_t)s3 * 64 + lane];
        float p0 = expf(lrelu(e0 + ad));
        float p1 = expf(lrelu(e1 + ad));
        float p2 = expf(lrelu(e2 + ad));
        float p3 = expf(lrelu(e3 + ad));
        den += p0 + p1 + p2 + p3;
        acc = fmaf(p0, x0, acc);
        acc = fmaf(p1, x1, acc);
        acc = fmaf(p2, x2, acc);
        acc = fmaf(p3, x3, acc);
    }
    for (; idx < end; ++idx) {
        int src = adj[idx];
        float p = expf(lrelu(As[(size_t)src * 8 + h] + ad));
        den += p;
        acc = fmaf(p, XW[(size_t)src * 64 + lane], acc);
    }

    float v = fmaxf(acc / (den + 1e-16f) + bias[lane], 0.f);
    OUT[(size_t)node * 64 + lane] = v;

    if (WITH_A3) {
        float s3 = v * w_as[lane];
        float d3 = v * w_ad[lane];
#pragma unroll
        for (int m = 1; m <= 32; m <<= 1) {
            s3 += __shfl_xor(s3, m);
            d3 += __shfl_xor(d3, m);
        }
        if (lane == 0) {
            As3[node] = s3;
            Ad3[node] = d3;
        }
    }
}

// ---------------- Layer 3 aggregation in h-space (no LDS, high occupancy) --
// MSG[node][64] = sum_e p_e * H2[src_e] / sum_e p_e

__global__ __launch_bounds__(256)
void agg3msg_kernel(const float* __restrict__ H2, const float* __restrict__ As3,
                    const float* __restrict__ Ad3, const int* __restrict__ row_ptr,
                    const int* __restrict__ adj, float* __restrict__ MSG, int N) {
    int wave = threadIdx.x >> 6, lane = threadIdx.x & 63;
    int node = blockIdx.x * 4 + wave;
    if (node >= N) return;
    int beg = row_ptr[node], end = row_ptr[node + 1];
    float ad = Ad3[node];

    float acc = 0.f, den = 0.f;
    int idx = beg;
    for (; idx + 4 <= end; idx += 4) {
        int s0 = adj[idx], s1 = adj[idx + 1], s2 = adj[idx + 2], s3 = adj[idx + 3];
        float e0 = As3[s0], e1 = As3[s1], e2 = As3[s2], e3 = As3[s3];
        float x0 = H2[(size_t)s0 * 64 + lane];
        float x1 = H2[(size_t)s1 * 64 + lane];
        float x2 = H2[(size_t)s2 * 64 + lane];
        float x3 = H2[(size_t)s3 * 64 + lane];
        float p0 = expf(lrelu(e0 + ad));
        float p1 = expf(lrelu(e1 + ad));
        float p2 = expf(lrelu(e2 + ad));
        float p3 = expf(lrelu(e3 + ad));
        den += p0 + p1 + p2 + p3;
        acc = fmaf(p0, x0, acc);
        acc = fmaf(p1, x1, acc);
        acc = fmaf(p2, x2, acc);
        acc = fmaf(p3, x3, acc);
    }
    for (; idx < end; ++idx) {
        int src = adj[idx];
        float p = expf(lrelu(As3[src] + ad));
        den += p;
        acc = fmaf(p, H2[(size_t)src * 64 + lane], acc);
    }
    MSG[(size_t)node * 64 + lane] = acc / (den + 1e-16f);
}

// ---------------- gemm3: OUT = softmax_pairs(relu(MSG @ W3 + b3)) ----------
// W3 staged in LDS once per block; 16 nodes per block (4 per wave).

__global__ __launch_bounds__(256)
void gemm3_kernel(const float* __restrict__ MSG, const float* __restrict__ W3,
                  const float* __restrict__ bias, float* __restrict__ OUT, int N) {
    __shared__ float w3sh[64 * 244];  // stride 244 for float4 + pad
    __shared__ float msh[4][64];
    for (int i = threadIdx.x; i < 64 * 242; i += 256) {
        int k = i / 242, c = i - k * 242;
        w3sh[k * 244 + c] = W3[i];
    }
    if (threadIdx.x < 64) {
        w3sh[threadIdx.x * 244 + 242] = 0.f;
        w3sh[threadIdx.x * 244 + 243] = 0.f;
    }
    __syncthreads();

    int wave = threadIdx.x >> 6, lane = threadIdx.x & 63;
    int c0 = lane * 4;  // lanes 0..60 carry channels

#pragma unroll
    for (int i = 0; i < 4; ++i) {
        int node = blockIdx.x * 16 + wave * 4 + i;
        if (node >= N) break;
        msh[wave][lane] = MSG[(size_t)node * 64 + lane];  // same-wave LDS RAW: in-order DS pipe
        if (c0 < 242) {
            float o0 = 0.f, o1 = 0.f, o2 = 0.f, o3 = 0.f;
#pragma unroll 8
            for (int k = 0; k < 64; ++k) {
                float m = msh[wave][k];
                const float4 w = *(const float4*)(w3sh + k * 244 + c0);
                o0 = fmaf(m, w.x, o0);
                o1 = fmaf(m, w.y, o1);
                o2 = fmaf(m, w.z, o2);
                o3 = fmaf(m, w.w, o3);
            }
            size_t base = (size_t)node * 242 + c0;
            float v0 = fmaxf(o0 + bias[c0], 0.f);
            float v1 = fmaxf(o1 + bias[c0 + 1], 0.f);
            float m01 = fmaxf(v0, v1);
            float e0 = expf(v0 - m01), e1 = expf(v1 - m01);
            float r01 = 1.f / (e0 + e1);
            OUT[base]     = e0 * r01;
            OUT[base + 1] = e1 * r01;
            if (c0 + 2 < 242) {
                float v2 = fmaxf(o2 + bias[c0 + 2], 0.f);
                float v3 = fmaxf(o3 + bias[c0 + 3], 0.f);
                float m23 = fmaxf(v2, v3);
                float e2 = expf(v2 - m23), e3 = expf(v3 - m23);
                float r23 = 1.f / (e2 + e3);
                OUT[base + 2] = e2 * r23;
                OUT[base + 3] = e3 * r23;
            }
        }
    }
}

// ---------------- launch ----------------

extern "C" void kernel_launch(void* const* d_in, const int* in_sizes, int n_in,
                              void* d_out, int out_size, void* d_ws, size_t ws_size,
                              hipStream_t stream) {
    const float* x   = (const float*)d_in[0];
    const void*  ei  = d_in[1];
    const float* W1  = (const float*)d_in[2];
    const float* a1s = (const float*)d_in[3];
    const float* a1d = (const float*)d_in[4];
    const float* b1  = (const float*)d_in[5];
    const float* W2  = (const float*)d_in[6];
    const float* a2s = (const float*)d_in[7];
    const float* a2d = (const float*)d_in[8];
    const float* b2  = (const float*)d_in[9];
    const float* W3  = (const float*)d_in[10];
    const float* a3s = (const float*)d_in[11];
    const float* a3d = (const float*)d_in[12];
    const float* b3  = (const float*)d_in[13];
    float* out = (float*)d_out;

    const int N = in_sizes[0] / 128;  // 50000
    const int E = in_sizes[1] / 2;    // 800000

    char* w = (char*)d_ws;
    auto alloc = [&](size_t bytes) {
        char* p = w;
        w += (bytes + 255) & ~(size_t)255;
        return p;
    };
    int*   flag    = (int*)alloc(4);
    int*   deg     = (int*)alloc((size_t)N * 4);
    int*   row_ptr = (int*)alloc(((size_t)N + 1) * 4);
    int*   cursor  = (int*)alloc((size_t)N * 4);
    int*   adj     = (int*)alloc((size_t)(E + N) * 4);
    float* As      = (float*)alloc((size_t)N * 8 * 4);
    float* Ad      = (float*)alloc((size_t)N * 8 * 4);
    float* As3     = (float*)alloc((size_t)N * 4);
    float* Ad3     = (float*)alloc((size_t)N * 4);
    float* w_as    = (float*)alloc(64 * 4);
    float* w_ad    = (float*)alloc(64 * 4);
    float* bufA    = (float*)alloc((size_t)N * 64 * 4);
    float* bufB    = (float*)alloc((size_t)N * 64 * 4);

    // CSR over dst (includes self-loops)
    detect_kernel<<<1, 64, 0, stream>>>((const int*)ei, flag);
    deg_init_kernel<<<(N + 255) / 256, 256, 0, stream>>>(deg, N);
    deg_count_kernel<<<(E + 255) / 256, 256, 0, stream>>>(ei, flag, deg, E);
    scan_kernel<<<1, 1024, 0, stream>>>(deg, row_ptr, cursor, N);
    scatter_kernel<<<(E + N + 255) / 256, 256, 0, stream>>>(ei, flag, cursor, adj, E, N);
    w3a_kernel<<<1, 128, 0, stream>>>(W3, a3s, a3d, w_as, w_ad);

    int nb4 = (N + 3) / 4;

    // Layer 1: x -> bufA (xw1), agg -> bufB (h1)
    gemm_alpha8<128><<<nb4, 256, 0, stream>>>(x, W1, a1s, a1d, bufA, As, Ad, N);
    agg_h8c8<false><<<nb4, 256, 0, stream>>>(bufA, As, Ad, row_ptr, adj, b1, bufB,
                                             nullptr, nullptr, nullptr, nullptr, N);
    // Layer 2: bufB -> bufB in-place (xw2), agg -> bufA (h2) + As3/Ad3 epilogue
    gemm_alpha8<64><<<nb4, 256, 0, stream>>>(bufB, W2, a2s, a2d, bufB, As, Ad, N);
    agg_h8c8<true><<<nb4, 256, 0, stream>>>(bufB, As, Ad, row_ptr, adj, b2, bufA,
                                            w_as, w_ad, As3, Ad3, N);
    // Layer 3: h-space aggregation (bufA -> bufB), then fused gemm3 -> out
    agg3msg_kernel<<<nb4, 256, 0, stream>>>(bufA, As3, Ad3, row_ptr, adj, bufB, N);
    gemm3_kernel<<<(N + 15) / 16, 256, 0, stream>>>(bufB, W3, b3, out, N);
}

// Round 9
// 483.838 us; speedup vs baseline: 2.0519x; 1.2414x over previous
//
#include <hip/hip_runtime.h>
#include <hip/hip_bf16.h>

// GAT 3-layer (PPI-style) on MI355X. fp32 tensors; edge_index (2,E) planar,
// int32/int64 via device flag. R8 -> R9:
// (1) single-block scan (111us, 0.14% occupancy) replaced by 3-phase
//     multi-block scan (~12us);
// (2) __expf (v_exp_f32) + 8x unroll in aggregation hot loops;
// (3) gemm_alpha8 processes 16 nodes/block (4/wave) -> 4x fewer W restages.

__device__ __forceinline__ float lrelu(float s) { return (s >= 0.f) ? s : 0.2f * s; }

// ---------------- edge dtype detection: (2,E) planar ----------------

__global__ void detect_kernel(const int* __restrict__ ei, int* __restrict__ flag) {
    int t = threadIdx.x;  // 64 lanes
    int v = ei[2 * t + 1];
    unsigned long long b = __ballot(v == 0);
    if (t == 0) *flag = (b == ~0ULL) ? 1 : 0;
}

__device__ __forceinline__ int edge_at(const void* ei, int is64, long long idx) {
    return is64 ? (int)((const long long*)ei)[idx] : ((const int*)ei)[idx];
}

// ---------------- CSR build ----------------

__global__ void deg_init_kernel(int* __restrict__ deg, int N) {
    int t = blockIdx.x * blockDim.x + threadIdx.x;
    if (t < N) deg[t] = 1;  // self-loop
}

__global__ void deg_count_kernel(const void* __restrict__ ei, const int* __restrict__ flag,
                                 int* __restrict__ deg, int E) {
    int t = blockIdx.x * blockDim.x + threadIdx.x;
    if (t < E) {
        int dst = edge_at(ei, *flag, (long long)E + t);  // row 1 = dst
        atomicAdd(&deg[dst], 1);
    }
}

// 3-phase multi-block exclusive scan of deg[0..N) -> row_ptr/cursor.
// Phase A: per-block (256-elem tile) sums.
__global__ __launch_bounds__(256)
void scanA_kernel(const int* __restrict__ deg, int* __restrict__ bsum, int N) {
    __shared__ int red[256];
    int t = threadIdx.x;
    int i = blockIdx.x * 256 + t;
    red[t] = (i < N) ? deg[i] : 0;
    __syncthreads();
#pragma unroll
    for (int off = 128; off > 0; off >>= 1) {
        if (t < off) red[t] += red[t + off];
        __syncthreads();
    }
    if (t == 0) bsum[blockIdx.x] = red[0];
}

// Phase B: exclusive scan of nb (<=256) block sums; writes total to row_ptrN.
__global__ __launch_bounds__(256)
void scanB_kernel(const int* __restrict__ bsum, int* __restrict__ boff,
                  int* __restrict__ row_ptrN, int nb) {
    __shared__ int s[256];
    int t = threadIdx.x;
    int v = (t < nb) ? bsum[t] : 0;
    s[t] = v;
    __syncthreads();
#pragma unroll
    for (int off = 1; off < 256; off <<= 1) {
        int u = (t >= off) ? s[t - off] : 0;
        __syncthreads();
        s[t] += u;
        __syncthreads();
    }
    if (t < nb) boff[t] = s[t] - v;  // exclusive
    if (t == nb - 1) *row_ptrN = s[t];
}

// Phase C: block-local exclusive scan + block offset -> row_ptr & cursor.
__global__ __launch_bounds__(256)
void scanC_kernel(const int* __restrict__ deg, const int* __restrict__ boff,
                  int* __restrict__ row_ptr, int* __restrict__ cursor, int N) {
    __shared__ int s[256];
    int t = threadIdx.x;
    int i = blockIdx.x * 256 + t;
    int v = (i < N) ? deg[i] : 0;
    s[t] = v;
    __syncthreads();
#pragma unroll
    for (int off = 1; off < 256; off <<= 1) {
        int u = (t >= off) ? s[t - off] : 0;
        __syncthreads();
        s[t] += u;
        __syncthreads();
    }
    if (i < N) {
        int ex = boff[blockIdx.x] + s[t] - v;
        row_ptr[i] = ex;
        cursor[i] = ex;
    }
}

__global__ void scatter_kernel(const void* __restrict__ ei, const int* __restrict__ flag,
                               int* __restrict__ cursor, int* __restrict__ adj, int E, int N) {
    int t = blockIdx.x * blockDim.x + threadIdx.x;
    if (t < E) {
        int is64 = *flag;
        int src = edge_at(ei, is64, t);
        int dst = edge_at(ei, is64, (long long)E + t);
        int pos = atomicAdd(&cursor[dst], 1);
        adj[pos] = src;
    } else if (t < E + N) {
        int n2 = t - E;
        int pos = atomicAdd(&cursor[n2], 1);
        adj[pos] = n2;  // self-loop
    }
}

// ---------------- w_as = W3 @ a3_src, w_ad = W3 @ a3_dst (64 each) --------

__global__ void w3a_kernel(const float* __restrict__ W3,
                           const float* __restrict__ a3s,
                           const float* __restrict__ a3d,
                           float* __restrict__ w_as, float* __restrict__ w_ad) {
    int t = threadIdx.x;  // 128 threads
    if (t >= 128) return;
    int k = t & 63;
    const float* a = (t < 64) ? a3s : a3d;
    float s = 0.f;
    for (int c = 0; c < 242; ++c) s = fmaf(W3[k * 242 + c], a[c], s);
    if (t < 64) w_as[k] = s; else w_ad[k] = s;
}

// ---------------- GEMM + alpha (layers 1 & 2: 64 cols, H=8, C=8) -----------
// 16 nodes per block (4 per wave) to amortize the W staging. Safe in-place
// (X==XW): all 16 rows staged to LDS before the barrier; writes after.

template <int K>
__global__ __launch_bounds__(256)
void gemm_alpha8(const float* __restrict__ X, const float* __restrict__ W,
                 const float* __restrict__ a_src, const float* __restrict__ a_dst,
                 float* __restrict__ XW, float* __restrict__ As, float* __restrict__ Ad,
                 int N) {
    __shared__ float wsh[K * 64];
    __shared__ float xsh[16][K];
    for (int i = threadIdx.x; i < K * 64; i += 256) wsh[i] = W[i];
    int wave = threadIdx.x >> 6, lane = threadIdx.x & 63;
    int base = blockIdx.x * 16 + wave * 4;
#pragma unroll
    for (int j = 0; j < 4; ++j) {
        int node = base + j;
        const float* xr = X + (size_t)(node < N ? node : 0) * K;
        for (int i = lane; i < K; i += 64) xsh[wave * 4 + j][i] = xr[i];
    }
    __syncthreads();
    int h = lane >> 3, c = lane & 7;
    float asv = a_src[h * 8 + c], adv = a_dst[h * 8 + c];
#pragma unroll
    for (int j = 0; j < 4; ++j) {
        int node = base + j;
        if (node >= N) break;
        const float* xs = xsh[wave * 4 + j];
        float acc = 0.f;
#pragma unroll 8
        for (int k = 0; k < K; ++k) acc = fmaf(xs[k], wsh[k * 64 + lane], acc);
        XW[(size_t)node * 64 + lane] = acc;
        float s = acc * asv;
        float d = acc * adv;
        s += __shfl_xor(s, 1); s += __shfl_xor(s, 2); s += __shfl_xor(s, 4);
        d += __shfl_xor(d, 1); d += __shfl_xor(d, 2); d += __shfl_xor(d, 4);
        if (c == 0) {
            As[node * 8 + h] = s;
            Ad[node * 8 + h] = d;
        }
    }
}

// ---------------- Aggregation (layers 1 & 2): one wave per dst node --------
// Single pass; every lane sees every edge so den accumulates per-lane.
// 8x unroll for memory-level parallelism; __expf (v_exp_f32).

template <bool WITH_A3>
__global__ __launch_bounds__(256)
void agg_h8c8(const float* __restrict__ XW, const float* __restrict__ As,
              const float* __restrict__ Ad, const int* __restrict__ row_ptr,
              const int* __restrict__ adj, const float* __restrict__ bias,
              float* __restrict__ OUT,
              const float* __restrict__ w_as, const float* __restrict__ w_ad,
              float* __restrict__ As3, float* __restrict__ Ad3, int N) {
    int wave = threadIdx.x >> 6, lane = threadIdx.x & 63;
    int node = blockIdx.x * 4 + wave;
    if (node >= N) return;
    int beg = row_ptr[node], end = row_ptr[node + 1];
    int h = lane >> 3;
    float ad = Ad[node * 8 + h];

    float acc = 0.f, den = 0.f;
    int idx = beg;
    for (; idx + 8 <= end; idx += 8) {
        int s[8];
        float e[8], x[8];
#pragma unroll
        for (int k = 0; k < 8; ++k) s[k] = adj[idx + k];
#pragma unroll
        for (int k = 0; k < 8; ++k) e[k] = As[(size_t)s[k] * 8 + h];
#pragma unroll
        for (int k = 0; k < 8; ++k) x[k] = XW[(size_t)s[k] * 64 + lane];
#pragma unroll
        for (int k = 0; k < 8; ++k) {
            float p = __expf(lrelu(e[k] + ad));
            den += p;
            acc = fmaf(p, x[k], acc);
        }
    }
    for (; idx < end; ++idx) {
        int src = adj[idx];
        float p = __expf(lrelu(As[(size_t)src * 8 + h] + ad));
        den += p;
        acc = fmaf(p, XW[(size_t)src * 64 + lane], acc);
    }

    float v = fmaxf(acc / (den + 1e-16f) + bias[lane], 0.f);
    OUT[(size_t)node * 64 + lane] = v;

    if (WITH_A3) {
        float s3 = v * w_as[lane];
        float d3 = v * w_ad[lane];
#pragma unroll
        for (int m = 1; m <= 32; m <<= 1) {
            s3 += __shfl_xor(s3, m);
            d3 += __shfl_xor(d3, m);
        }
        if (lane == 0) {
            As3[node] = s3;
            Ad3[node] = d3;
        }
    }
}

// ---------------- Layer 3 aggregation in h-space (no LDS) ------------------

__global__ __launch_bounds__(256)
void agg3msg_kernel(const float* __restrict__ H2, const float* __restrict__ As3,
                    const float* __restrict__ Ad3, const int* __restrict__ row_ptr,
                    const int* __restrict__ adj, float* __restrict__ MSG, int N) {
    int wave = threadIdx.x >> 6, lane = threadIdx.x & 63;
    int node = blockIdx.x * 4 + wave;
    if (node >= N) return;
    int beg = row_ptr[node], end = row_ptr[node + 1];
    float ad = Ad3[node];

    float acc = 0.f, den = 0.f;
    int idx = beg;
    for (; idx + 8 <= end; idx += 8) {
        int s[8];
        float e[8], x[8];
#pragma unroll
        for (int k = 0; k < 8; ++k) s[k] = adj[idx + k];
#pragma unroll
        for (int k = 0; k < 8; ++k) e[k] = As3[s[k]];
#pragma unroll
        for (int k = 0; k < 8; ++k) x[k] = H2[(size_t)s[k] * 64 + lane];
#pragma unroll
        for (int k = 0; k < 8; ++k) {
            float p = __expf(lrelu(e[k] + ad));
            den += p;
            acc = fmaf(p, x[k], acc);
        }
    }
    for (; idx < end; ++idx) {
        int src = adj[idx];
        float p = __expf(lrelu(As3[src] + ad));
        den += p;
        acc = fmaf(p, H2[(size_t)src * 64 + lane], acc);
    }
    MSG[(size_t)node * 64 + lane] = acc / (den + 1e-16f);
}

// ---------------- gemm3: OUT = softmax_pairs(relu(MSG @ W3 + b3)) ----------

__global__ __launch_bounds__(256)
void gemm3_kernel(const float* __restrict__ MSG, const float* __restrict__ W3,
                  const float* __restrict__ bias, float* __restrict__ OUT, int N) {
    __shared__ float w3sh[64 * 244];
    __shared__ float msh[4][64];
    for (int i = threadIdx.x; i < 64 * 242; i += 256) {
        int k = i / 242, c = i - k * 242;
        w3sh[k * 244 + c] = W3[i];
    }
    if (threadIdx.x < 64) {
        w3sh[threadIdx.x * 244 + 242] = 0.f;
        w3sh[threadIdx.x * 244 + 243] = 0.f;
    }
    __syncthreads();

    int wave = threadIdx.x >> 6, lane = threadIdx.x & 63;
    int c0 = lane * 4;  // lanes 0..60 carry channels

#pragma unroll
    for (int i = 0; i < 4; ++i) {
        int node = blockIdx.x * 16 + wave * 4 + i;
        if (node >= N) break;
        msh[wave][lane] = MSG[(size_t)node * 64 + lane];  // same-wave LDS RAW
        if (c0 < 242) {
            float o0 = 0.f, o1 = 0.f, o2 = 0.f, o3 = 0.f;
#pragma unroll 8
            for (int k = 0; k < 64; ++k) {
                float m = msh[wave][k];
                const float4 w = *(const float4*)(w3sh + k * 244 + c0);
                o0 = fmaf(m, w.x, o0);
                o1 = fmaf(m, w.y, o1);
                o2 = fmaf(m, w.z, o2);
                o3 = fmaf(m, w.w, o3);
            }
            size_t base = (size_t)node * 242 + c0;
            float v0 = fmaxf(o0 + bias[c0], 0.f);
            float v1 = fmaxf(o1 + bias[c0 + 1], 0.f);
            float m01 = fmaxf(v0, v1);
            float e0 = __expf(v0 - m01), e1 = __expf(v1 - m01);
            float r01 = 1.f / (e0 + e1);
            OUT[base]     = e0 * r01;
            OUT[base + 1] = e1 * r01;
            if (c0 + 2 < 242) {
                float v2 = fmaxf(o2 + bias[c0 + 2], 0.f);
                float v3 = fmaxf(o3 + bias[c0 + 3], 0.f);
                float m23 = fmaxf(v2, v3);
                float e2 = __expf(v2 - m23), e3 = __expf(v3 - m23);
                float r23 = 1.f / (e2 + e3);
                OUT[base + 2] = e2 * r23;
                OUT[base + 3] = e3 * r23;
            }
        }
    }
}

// ---------------- launch ----------------

extern "C" void kernel_launch(void* const* d_in, const int* in_sizes, int n_in,
                              void* d_out, int out_size, void* d_ws, size_t ws_size,
                              hipStream_t stream) {
    const float* x   = (const float*)d_in[0];
    const void*  ei  = d_in[1];
    const float* W1  = (const float*)d_in[2];
    const float* a1s = (const float*)d_in[3];
    const float* a1d = (const float*)d_in[4];
    const float* b1  = (const float*)d_in[5];
    const float* W2  = (const float*)d_in[6];
    const float* a2s = (const float*)d_in[7];
    const float* a2d = (const float*)d_in[8];
    const float* b2  = (const float*)d_in[9];
    const float* W3  = (const float*)d_in[10];
    const float* a3s = (const float*)d_in[11];
    const float* a3d = (const float*)d_in[12];
    const float* b3  = (const float*)d_in[13];
    float* out = (float*)d_out;

    const int N = in_sizes[0] / 128;  // 50000
    const int E = in_sizes[1] / 2;    // 800000

    char* w = (char*)d_ws;
    auto alloc = [&](size_t bytes) {
        char* p = w;
        w += (bytes + 255) & ~(size_t)255;
        return p;
    };
    int*   flag    = (int*)alloc(4);
    int*   deg     = (int*)alloc((size_t)N * 4);
    int*   row_ptr = (int*)alloc(((size_t)N + 1) * 4);
    int*   cursor  = (int*)alloc((size_t)N * 4);
    int*   bsum    = (int*)alloc(256 * 4);
    int*   boff    = (int*)alloc(256 * 4);
    int*   adj     = (int*)alloc((size_t)(E + N) * 4);
    float* As      = (float*)alloc((size_t)N * 8 * 4);
    float* Ad      = (float*)alloc((size_t)N * 8 * 4);
    float* As3     = (float*)alloc((size_t)N * 4);
    float* Ad3     = (float*)alloc((size_t)N * 4);
    float* w_as    = (float*)alloc(64 * 4);
    float* w_ad    = (float*)alloc(64 * 4);
    float* bufA    = (float*)alloc((size_t)N * 64 * 4);
    float* bufB    = (float*)alloc((size_t)N * 64 * 4);

    int nbs = (N + 255) / 256;  // 196 <= 256

    // CSR over dst (includes self-loops)
    detect_kernel<<<1, 64, 0, stream>>>((const int*)ei, flag);
    deg_init_kernel<<<nbs, 256, 0, stream>>>(deg, N);
    deg_count_kernel<<<(E + 255) / 256, 256, 0, stream>>>(ei, flag, deg, E);
    scanA_kernel<<<nbs, 256, 0, stream>>>(deg, bsum, N);
    scanB_kernel<<<1, 256, 0, stream>>>(bsum, boff, row_ptr + N, nbs);
    scanC_kernel<<<nbs, 256, 0, stream>>>(deg, boff, row_ptr, cursor, N);
    scatter_kernel<<<(E + N + 255) / 256, 256, 0, stream>>>(ei, flag, cursor, adj, E, N);
    w3a_kernel<<<1, 128, 0, stream>>>(W3, a3s, a3d, w_as, w_ad);

    int nb4 = (N + 3) / 4;
    int nb16 = (N + 15) / 16;

    // Layer 1: x -> bufA (xw1), agg -> bufB (h1)
    gemm_alpha8<128><<<nb16, 256, 0, stream>>>(x, W1, a1s, a1d, bufA, As, Ad, N);
    agg_h8c8<false><<<nb4, 256, 0, stream>>>(bufA, As, Ad, row_ptr, adj, b1, bufB,
                                             nullptr, nullptr, nullptr, nullptr, N);
    // Layer 2: bufB -> bufB in-place (xw2), agg -> bufA (h2) + As3/Ad3 epilogue
    gemm_alpha8<64><<<nb16, 256, 0, stream>>>(bufB, W2, a2s, a2d, bufB, As, Ad, N);
    agg_h8c8<true><<<nb4, 256, 0, stream>>>(bufB, As, Ad, row_ptr, adj, b2, bufA,
                                            w_as, w_ad, As3, Ad3, N);
    // Layer 3: h-space aggregation (bufA -> bufB), then fused gemm3 -> out
    agg3msg_kernel<<<nb4, 256, 0, stream>>>(bufA, As3, Ad3, row_ptr, adj, bufB, N);
    gemm3_kernel<<<nb16, 256, 0, stream>>>(bufB, W3, b3, out, N);
}

// Round 10
// 449.071 us; speedup vs baseline: 2.2108x; 1.0774x over previous
//
#include <hip/hip_runtime.h>
#include <hip/hip_bf16.h>

// GAT 3-layer (PPI-style) on MI355X. fp32 tensors; edge_index (2,E) planar,
// int32/int64 via device flag. R9 -> R10:
// gemm3 was LDS-bound (each node re-read all 62KB of W3 from LDS; 2 blocks/CU).
// New gemm3: W3 pre-padded to stride-244 in workspace, streamed from global
// (L2-resident, 16B-aligned float4); 8 nodes register-blocked per wave so each
// W3 load feeds 32 FMAs; only an 8KB MSG tile in LDS -> high occupancy.

__device__ __forceinline__ float lrelu(float s) { return (s >= 0.f) ? s : 0.2f * s; }

// ---------------- edge dtype detection: (2,E) planar ----------------

__global__ void detect_kernel(const int* __restrict__ ei, int* __restrict__ flag) {
    int t = threadIdx.x;  // 64 lanes
    int v = ei[2 * t + 1];
    unsigned long long b = __ballot(v == 0);
    if (t == 0) *flag = (b == ~0ULL) ? 1 : 0;
}

__device__ __forceinline__ int edge_at(const void* ei, int is64, long long idx) {
    return is64 ? (int)((const long long*)ei)[idx] : ((const int*)ei)[idx];
}

// ---------------- CSR build ----------------

__global__ void deg_init_kernel(int* __restrict__ deg, int N) {
    int t = blockIdx.x * blockDim.x + threadIdx.x;
    if (t < N) deg[t] = 1;  // self-loop
}

__global__ void deg_count_kernel(const void* __restrict__ ei, const int* __restrict__ flag,
                                 int* __restrict__ deg, int E) {
    int t = blockIdx.x * blockDim.x + threadIdx.x;
    if (t < E) {
        int dst = edge_at(ei, *flag, (long long)E + t);  // row 1 = dst
        atomicAdd(&deg[dst], 1);
    }
}

// 3-phase multi-block exclusive scan of deg[0..N) -> row_ptr/cursor.
__global__ __launch_bounds__(256)
void scanA_kernel(const int* __restrict__ deg, int* __restrict__ bsum, int N) {
    __shared__ int red[256];
    int t = threadIdx.x;
    int i = blockIdx.x * 256 + t;
    red[t] = (i < N) ? deg[i] : 0;
    __syncthreads();
#pragma unroll
    for (int off = 128; off > 0; off >>= 1) {
        if (t < off) red[t] += red[t + off];
        __syncthreads();
    }
    if (t == 0) bsum[blockIdx.x] = red[0];
}

__global__ __launch_bounds__(256)
void scanB_kernel(const int* __restrict__ bsum, int* __restrict__ boff,
                  int* __restrict__ row_ptrN, int nb) {
    __shared__ int s[256];
    int t = threadIdx.x;
    int v = (t < nb) ? bsum[t] : 0;
    s[t] = v;
    __syncthreads();
#pragma unroll
    for (int off = 1; off < 256; off <<= 1) {
        int u = (t >= off) ? s[t - off] : 0;
        __syncthreads();
        s[t] += u;
        __syncthreads();
    }
    if (t < nb) boff[t] = s[t] - v;  // exclusive
    if (t == nb - 1) *row_ptrN = s[t];
}

__global__ __launch_bounds__(256)
void scanC_kernel(const int* __restrict__ deg, const int* __restrict__ boff,
                  int* __restrict__ row_ptr, int* __restrict__ cursor, int N) {
    __shared__ int s[256];
    int t = threadIdx.x;
    int i = blockIdx.x * 256 + t;
    int v = (i < N) ? deg[i] : 0;
    s[t] = v;
    __syncthreads();
#pragma unroll
    for (int off = 1; off < 256; off <<= 1) {
        int u = (t >= off) ? s[t - off] : 0;
        __syncthreads();
        s[t] += u;
        __syncthreads();
    }
    if (i < N) {
        int ex = boff[blockIdx.x] + s[t] - v;
        row_ptr[i] = ex;
        cursor[i] = ex;
    }
}

__global__ void scatter_kernel(const void* __restrict__ ei, const int* __restrict__ flag,
                               int* __restrict__ cursor, int* __restrict__ adj, int E, int N) {
    int t = blockIdx.x * blockDim.x + threadIdx.x;
    if (t < E) {
        int is64 = *flag;
        int src = edge_at(ei, is64, t);
        int dst = edge_at(ei, is64, (long long)E + t);
        int pos = atomicAdd(&cursor[dst], 1);
        adj[pos] = src;
    } else if (t < E + N) {
        int n2 = t - E;
        int pos = atomicAdd(&cursor[n2], 1);
        adj[pos] = n2;  // self-loop
    }
}

// ---- w_as = W3 @ a3_src, w_ad = W3 @ a3_dst; and W3 padded to stride 244 ---

__global__ void w3a_kernel(const float* __restrict__ W3,
                           const float* __restrict__ a3s,
                           const float* __restrict__ a3d,
                           float* __restrict__ w_as, float* __restrict__ w_ad) {
    int t = threadIdx.x;  // 128 threads
    if (t >= 128) return;
    int k = t & 63;
    const float* a = (t < 64) ? a3s : a3d;
    float s = 0.f;
    for (int c = 0; c < 242; ++c) s = fmaf(W3[k * 242 + c], a[c], s);
    if (t < 64) w_as[k] = s; else w_ad[k] = s;
}

__global__ __launch_bounds__(256)
void w3pad_kernel(const float* __restrict__ W3, float* __restrict__ W3p) {
    int t = blockIdx.x * blockDim.x + threadIdx.x;  // 64*244
    if (t >= 64 * 244) return;
    int k = t / 244, c = t - k * 244;
    W3p[t] = (c < 242) ? W3[k * 242 + c] : 0.f;
}

// ---------------- GEMM + alpha (layers 1 & 2: 64 cols, H=8, C=8) -----------
// 16 nodes per block (4 per wave). Safe in-place (X==XW).

template <int K>
__global__ __launch_bounds__(256)
void gemm_alpha8(const float* __restrict__ X, const float* __restrict__ W,
                 const float* __restrict__ a_src, const float* __restrict__ a_dst,
                 float* __restrict__ XW, float* __restrict__ As, float* __restrict__ Ad,
                 int N) {
    __shared__ float wsh[K * 64];
    __shared__ float xsh[16][K];
    for (int i = threadIdx.x; i < K * 64; i += 256) wsh[i] = W[i];
    int wave = threadIdx.x >> 6, lane = threadIdx.x & 63;
    int base = blockIdx.x * 16 + wave * 4;
#pragma unroll
    for (int j = 0; j < 4; ++j) {
        int node = base + j;
        const float* xr = X + (size_t)(node < N ? node : 0) * K;
        for (int i = lane; i < K; i += 64) xsh[wave * 4 + j][i] = xr[i];
    }
    __syncthreads();
    int h = lane >> 3, c = lane & 7;
    float asv = a_src[h * 8 + c], adv = a_dst[h * 8 + c];
#pragma unroll
    for (int j = 0; j < 4; ++j) {
        int node = base + j;
        if (node >= N) break;
        const float* xs = xsh[wave * 4 + j];
        float acc = 0.f;
#pragma unroll 8
        for (int k = 0; k < K; ++k) acc = fmaf(xs[k], wsh[k * 64 + lane], acc);
        XW[(size_t)node * 64 + lane] = acc;
        float s = acc * asv;
        float d = acc * adv;
        s += __shfl_xor(s, 1); s += __shfl_xor(s, 2); s += __shfl_xor(s, 4);
        d += __shfl_xor(d, 1); d += __shfl_xor(d, 2); d += __shfl_xor(d, 4);
        if (c == 0) {
            As[node * 8 + h] = s;
            Ad[node * 8 + h] = d;
        }
    }
}

// ---------------- Aggregation (layers 1 & 2): one wave per dst node --------

template <bool WITH_A3>
__global__ __launch_bounds__(256)
void agg_h8c8(const float* __restrict__ XW, const float* __restrict__ As,
              const float* __restrict__ Ad, const int* __restrict__ row_ptr,
              const int* __restrict__ adj, const float* __restrict__ bias,
              float* __restrict__ OUT,
              const float* __restrict__ w_as, const float* __restrict__ w_ad,
              float* __restrict__ As3, float* __restrict__ Ad3, int N) {
    int wave = threadIdx.x >> 6, lane = threadIdx.x & 63;
    int node = blockIdx.x * 4 + wave;
    if (node >= N) return;
    int beg = row_ptr[node], end = row_ptr[node + 1];
    int h = lane >> 3;
    float ad = Ad[node * 8 + h];

    float acc = 0.f, den = 0.f;
    int idx = beg;
    for (; idx + 8 <= end; idx += 8) {
        int s[8];
        float e[8], x[8];
#pragma unroll
        for (int k = 0; k < 8; ++k) s[k] = adj[idx + k];
#pragma unroll
        for (int k = 0; k < 8; ++k) e[k] = As[(size_t)s[k] * 8 + h];
#pragma unroll
        for (int k = 0; k < 8; ++k) x[k] = XW[(size_t)s[k] * 64 + lane];
#pragma unroll
        for (int k = 0; k < 8; ++k) {
            float p = __expf(lrelu(e[k] + ad));
            den += p;
            acc = fmaf(p, x[k], acc);
        }
    }
    for (; idx < end; ++idx) {
        int src = adj[idx];
        float p = __expf(lrelu(As[(size_t)src * 8 + h] + ad));
        den += p;
        acc = fmaf(p, XW[(size_t)src * 64 + lane], acc);
    }

    float v = fmaxf(acc / (den + 1e-16f) + bias[lane], 0.f);
    OUT[(size_t)node * 64 + lane] = v;

    if (WITH_A3) {
        float s3 = v * w_as[lane];
        float d3 = v * w_ad[lane];
#pragma unroll
        for (int m = 1; m <= 32; m <<= 1) {
            s3 += __shfl_xor(s3, m);
            d3 += __shfl_xor(d3, m);
        }
        if (lane == 0) {
            As3[node] = s3;
            Ad3[node] = d3;
        }
    }
}

// ---------------- Layer 3 aggregation in h-space (no LDS) ------------------

__global__ __launch_bounds__(256)
void agg3msg_kernel(const float* __restrict__ H2, const float* __restrict__ As3,
                    const float* __restrict__ Ad3, const int* __restrict__ row_ptr,
                    const int* __restrict__ adj, float* __restrict__ MSG, int N) {
    int wave = threadIdx.x >> 6, lane = threadIdx.x & 63;
    int node = blockIdx.x * 4 + wave;
    if (node >= N) return;
    int beg = row_ptr[node], end = row_ptr[node + 1];
    float ad = Ad3[node];

    float acc = 0.f, den = 0.f;
    int idx = beg;
    for (; idx + 8 <= end; idx += 8) {
        int s[8];
        float e[8], x[8];
#pragma unroll
        for (int k = 0; k < 8; ++k) s[k] = adj[idx + k];
#pragma unroll
        for (int k = 0; k < 8; ++k) e[k] = As3[s[k]];
#pragma unroll
        for (int k = 0; k < 8; ++k) x[k] = H2[(size_t)s[k] * 64 + lane];
#pragma unroll
        for (int k = 0; k < 8; ++k) {
            float p = __expf(lrelu(e[k] + ad));
            den += p;
            acc = fmaf(p, x[k], acc);
        }
    }
    for (; idx < end; ++idx) {
        int src = adj[idx];
        float p = __expf(lrelu(As3[src] + ad));
        den += p;
        acc = fmaf(p, H2[(size_t)src * 64 + lane], acc);
    }
    MSG[(size_t)node * 64 + lane] = acc / (den + 1e-16f);
}

// ---------------- gemm3 v2: OUT = softmax_pairs(relu(MSG @ W3 + b3)) -------
// 8 nodes register-blocked per wave (32/block); W3p (stride 244) streamed
// from global (L2-resident); only the 8KB MSG tile in LDS.

__global__ __launch_bounds__(256)
void gemm3_kernel(const float* __restrict__ MSG, const float* __restrict__ W3p,
                  const float* __restrict__ bias, float* __restrict__ OUT, int N) {
    __shared__ float msh[4][8][64];
    int wave = threadIdx.x >> 6, lane = threadIdx.x & 63;
    int base = blockIdx.x * 32 + wave * 8;

#pragma unroll
    for (int j = 0; j < 8; ++j) {
        int node = base + j;
        msh[wave][j][lane] = (node < N) ? MSG[(size_t)node * 64 + lane] : 0.f;
    }
    // same-wave LDS RAW: DS pipe in-order, compiler inserts lgkmcnt wait

    int c0 = lane * 4;  // lanes 0..60 carry channels; 61-63 idle
    if (c0 < 242) {
        float o[8][4];
#pragma unroll
        for (int j = 0; j < 8; ++j)
#pragma unroll
            for (int q = 0; q < 4; ++q) o[j][q] = 0.f;

#pragma unroll 4
        for (int k = 0; k < 64; k += 4) {
            float4 w0 = *(const float4*)(W3p + (size_t)(k + 0) * 244 + c0);
            float4 w1 = *(const float4*)(W3p + (size_t)(k + 1) * 244 + c0);
            float4 w2 = *(const float4*)(W3p + (size_t)(k + 2) * 244 + c0);
            float4 w3 = *(const float4*)(W3p + (size_t)(k + 3) * 244 + c0);
#pragma unroll
            for (int j = 0; j < 8; ++j) {
                float4 m = *(const float4*)(&msh[wave][j][k]);
                o[j][0] = fmaf(m.x, w0.x, o[j][0]);
                o[j][1] = fmaf(m.x, w0.y, o[j][1]);
                o[j][2] = fmaf(m.x, w0.z, o[j][2]);
                o[j][3] = fmaf(m.x, w0.w, o[j][3]);
                o[j][0] = fmaf(m.y, w1.x, o[j][0]);
                o[j][1] = fmaf(m.y, w1.y, o[j][1]);
                o[j][2] = fmaf(m.y, w1.z, o[j][2]);
                o[j][3] = fmaf(m.y, w1.w, o[j][3]);
                o[j][0] = fmaf(m.z, w2.x, o[j][0]);
                o[j][1] = fmaf(m.z, w2.y, o[j][1]);
                o[j][2] = fmaf(m.z, w2.z, o[j][2]);
                o[j][3] = fmaf(m.z, w2.w, o[j][3]);
                o[j][0] = fmaf(m.w, w3.x, o[j][0]);
                o[j][1] = fmaf(m.w, w3.y, o[j][1]);
                o[j][2] = fmaf(m.w, w3.z, o[j][2]);
                o[j][3] = fmaf(m.w, w3.w, o[j][3]);
            }
        }

        float b0 = bias[c0], b1v = bias[c0 + 1];
        float b2v = (c0 + 2 < 242) ? bias[c0 + 2] : 0.f;
        float b3v = (c0 + 3 < 242) ? bias[c0 + 3] : 0.f;
#pragma unroll
        for (int j = 0; j < 8; ++j) {
            int node = base + j;
            if (node >= N) break;
            size_t out_base = (size_t)node * 242 + c0;
            float v0 = fmaxf(o[j][0] + b0, 0.f);
            float v1 = fmaxf(o[j][1] + b1v, 0.f);
            float m01 = fmaxf(v0, v1);
            float e0 = __expf(v0 - m01), e1 = __expf(v1 - m01);
            float r01 = 1.f / (e0 + e1);
            OUT[out_base]     = e0 * r01;
            OUT[out_base + 1] = e1 * r01;
            if (c0 + 2 < 242) {
                float v2 = fmaxf(o[j][2] + b2v, 0.f);
                float v3 = fmaxf(o[j][3] + b3v, 0.f);
                float m23 = fmaxf(v2, v3);
                float e2 = __expf(v2 - m23), e3 = __expf(v3 - m23);
                float r23 = 1.f / (e2 + e3);
                OUT[out_base + 2] = e2 * r23;
                OUT[out_base + 3] = e3 * r23;
            }
        }
    }
}

// ---------------- launch ----------------

extern "C" void kernel_launch(void* const* d_in, const int* in_sizes, int n_in,
                              void* d_out, int out_size, void* d_ws, size_t ws_size,
                              hipStream_t stream) {
    const float* x   = (const float*)d_in[0];
    const void*  ei  = d_in[1];
    const float* W1  = (const float*)d_in[2];
    const float* a1s = (const float*)d_in[3];
    const float* a1d = (const float*)d_in[4];
    const float* b1  = (const float*)d_in[5];
    const float* W2  = (const float*)d_in[6];
    const float* a2s = (const float*)d_in[7];
    const float* a2d = (const float*)d_in[8];
    const float* b2  = (const float*)d_in[9];
    const float* W3  = (const float*)d_in[10];
    const float* a3s = (const float*)d_in[11];
    const float* a3d = (const float*)d_in[12];
    const float* b3  = (const float*)d_in[13];
    float* out = (float*)d_out;

    const int N = in_sizes[0] / 128;  // 50000
    const int E = in_sizes[1] / 2;    // 800000

    char* w = (char*)d_ws;
    auto alloc = [&](size_t bytes) {
        char* p = w;
        w += (bytes + 255) & ~(size_t)255;
        return p;
    };
    int*   flag    = (int*)alloc(4);
    int*   deg     = (int*)alloc((size_t)N * 4);
    int*   row_ptr = (int*)alloc(((size_t)N + 1) * 4);
    int*   cursor  = (int*)alloc((size_t)N * 4);
    int*   bsum    = (int*)alloc(256 * 4);
    int*   boff    = (int*)alloc(256 * 4);
    int*   adj     = (int*)alloc((size_t)(E + N) * 4);
    float* As      = (float*)alloc((size_t)N * 8 * 4);
    float* Ad      = (float*)alloc((size_t)N * 8 * 4);
    float* As3     = (float*)alloc((size_t)N * 4);
    float* Ad3     = (float*)alloc((size_t)N * 4);
    float* w_as    = (float*)alloc(64 * 4);
    float* w_ad    = (float*)alloc(64 * 4);
    float* W3p     = (float*)alloc((size_t)64 * 244 * 4);
    float* bufA    = (float*)alloc((size_t)N * 64 * 4);
    float* bufB    = (float*)alloc((size_t)N * 64 * 4);

    int nbs = (N + 255) / 256;  // 196 <= 256

    // CSR over dst (includes self-loops)
    detect_kernel<<<1, 64, 0, stream>>>((const int*)ei, flag);
    deg_init_kernel<<<nbs, 256, 0, stream>>>(deg, N);
    deg_count_kernel<<<(E + 255) / 256, 256, 0, stream>>>(ei, flag, deg, E);
    scanA_kernel<<<nbs, 256, 0, stream>>>(deg, bsum, N);
    scanB_kernel<<<1, 256, 0, stream>>>(bsum, boff, row_ptr + N, nbs);
    scanC_kernel<<<nbs, 256, 0, stream>>>(deg, boff, row_ptr, cursor, N);
    scatter_kernel<<<(E + N + 255) / 256, 256, 0, stream>>>(ei, flag, cursor, adj, E, N);
    w3a_kernel<<<1, 128, 0, stream>>>(W3, a3s, a3d, w_as, w_ad);
    w3pad_kernel<<<(64 * 244 + 255) / 256, 256, 0, stream>>>(W3, W3p);

    int nb4 = (N + 3) / 4;
    int nb16 = (N + 15) / 16;
    int nb32 = (N + 31) / 32;

    // Layer 1: x -> bufA (xw1), agg -> bufB (h1)
    gemm_alpha8<128><<<nb16, 256, 0, stream>>>(x, W1, a1s, a1d, bufA, As, Ad, N);
    agg_h8c8<false><<<nb4, 256, 0, stream>>>(bufA, As, Ad, row_ptr, adj, b1, bufB,
                                             nullptr, nullptr, nullptr, nullptr, N);
    // Layer 2: bufB -> bufB in-place (xw2), agg -> bufA (h2) + As3/Ad3 epilogue
    gemm_alpha8<64><<<nb16, 256, 0, stream>>>(bufB, W2, a2s, a2d, bufB, As, Ad, N);
    agg_h8c8<true><<<nb4, 256, 0, stream>>>(bufB, As, Ad, row_ptr, adj, b2, bufA,
                                            w_as, w_ad, As3, Ad3, N);
    // Layer 3: h-space aggregation (bufA -> bufB), then gemm3 v2 -> out
    agg3msg_kernel<<<nb4, 256, 0, stream>>>(bufA, As3, Ad3, row_ptr, adj, bufB, N);
    gemm3_kernel<<<nb32, 256, 0, stream>>>(bufB, W3p, b3, out, N);
}